// Round 8
// baseline (272.057 us; speedup 1.0000x reference)
//
#include <hip/hip_runtime.h>
#include <math.h>

#define NLEV 8
#define D_DIM 1024

struct TB  { float  t[8]; };   // fp32 z-space thresholds (fast path)
struct TBD { double t[8]; };   // fp64 z-space thresholds (repair path)

// ---- DPP rotate-reduce within 16-lane rows (VALU pipe) ----
template<int CTRL>
__device__ __forceinline__ float ror_add(float v) {
    int r = __builtin_amdgcn_update_dpp(0, __float_as_int(v), CTRL, 0xF, 0xF, true);
    return v + __int_as_float(r);
}
__device__ __forceinline__ float red16(float v) {
    v = ror_add<0x121>(v);   // row_ror:1
    v = ror_add<0x122>(v);   // row_ror:2
    v = ror_add<0x124>(v);   // row_ror:4
    v = ror_add<0x128>(v);   // row_ror:8
    return v;                // all 16 lanes of each row hold the row sum
}
__device__ __forceinline__ float wave_allreduce(float v) {
    v = red16(v);
    v += __shfl_xor(v, 16, 64);
    v += __shfl_xor(v, 32, 64);
    return v;
}

// ---- fp64 repair, deferred: x RELOADED from global (L2-hot on this path) ----
// Inline, appears exactly once AFTER the hot loop; liveness disjoint from the
// hot loop's registers (R6 lesson: noinline ABI spilled; R7 lesson: nothing
// may be forced live across a big unrolled region).
__device__ __forceinline__ void repair_row_reload(
        int row, const float* __restrict__ xg,
        const float* __restrict__ gg, const float* __restrict__ bg,
        const float* __restrict__ Wg, float* __restrict__ outg,
        const TBD& tbd, int lane)
{
    const float4* xb4 = (const float4*)(xg + (size_t)row * D_DIM);
    const float4 x0 = xb4[lane];
    const float4 x1 = xb4[64 + lane];
    const float4 x2 = xb4[128 + lane];
    const float4 x3 = xb4[192 + lane];

    double ds = 0.0, dsq = 0.0;
    #pragma unroll
    for (int j = 0; j < 4; ++j) {
        const float4 a = (j == 0) ? x0 : (j == 1) ? x1 : (j == 2) ? x2 : x3;
        const double v0 = (double)a.x, v1 = (double)a.y;
        const double v2 = (double)a.z, v3 = (double)a.w;
        ds += ((v0 + v1) + (v2 + v3));
        dsq = fma(v0, v0, dsq); dsq = fma(v1, v1, dsq);
        dsq = fma(v2, v2, dsq); dsq = fma(v3, v3, dsq);
    }
    #pragma unroll
    for (int off = 32; off >= 1; off >>= 1) {
        ds  += __shfl_xor(ds, off, 64);
        dsq += __shfl_xor(dsq, off, 64);
    }
    const double mean = ds * (1.0 / 1024.0);
    const double var  = dsq * (1.0 / 1024.0) - mean * mean;
    const double rstd = 1.0 / sqrt(var + 1e-5);

    double dacc[NLEV];
    #pragma unroll
    for (int n = 0; n < NLEV; ++n) dacc[n] = 0.0;
    #pragma unroll
    for (int j = 0; j < 4; ++j) {
        const int col = j * 256 + lane * 4;
        const float4 a = (j == 0) ? x0 : (j == 1) ? x1 : (j == 2) ? x2 : x3;
        const float4 g4 = *(const float4*)(gg + col);
        const float4 b4 = *(const float4*)(bg + col);
        const double y0 = fma(((double)a.x - mean) * rstd, (double)g4.x, (double)b4.x);
        const double y1 = fma(((double)a.y - mean) * rstd, (double)g4.y, (double)b4.y);
        const double y2 = fma(((double)a.z - mean) * rstd, (double)g4.z, (double)b4.z);
        const double y3 = fma(((double)a.w - mean) * rstd, (double)g4.w, (double)b4.w);
        #pragma unroll
        for (int n = 0; n < NLEV; ++n) {
            const float4 w4 = *(const float4*)(Wg + n * D_DIM + col);
            dacc[n] = fma(y0, (double)w4.x, dacc[n]);
            dacc[n] = fma(y1, (double)w4.y, dacc[n]);
            dacc[n] = fma(y2, (double)w4.z, dacc[n]);
            dacc[n] = fma(y3, (double)w4.w, dacc[n]);
        }
    }
    #pragma unroll
    for (int off = 32; off >= 1; off >>= 1) {
        #pragma unroll
        for (int n = 0; n < NLEV; ++n) dacc[n] += __shfl_xor(dacc[n], off, 64);
    }
    if (lane < NLEV) {
        double a0d = (lane & 4) ? dacc[4] : dacc[0];
        double a1d = (lane & 4) ? dacc[5] : dacc[1];
        double a2d = (lane & 4) ? dacc[6] : dacc[2];
        double a3d = (lane & 4) ? dacc[7] : dacc[3];
        double b0d = (lane & 2) ? a2d : a0d;
        double b1d = (lane & 2) ? a3d : a1d;
        const double z = (lane & 1) ? b1d : b0d;
        int c = 0;
        #pragma unroll
        for (int k = 0; k < 8; ++k) c += (z > tbd.t[k]) ? 1 : 0;
        outg[(size_t)row * NLEV + lane] = (float)(c - 4);
    }
}

// ---- fp32 fast epilogue for one row; returns "ambiguous" flag ----
__device__ __forceinline__ bool fast_epilogue(
        int row, float s, float sq, float Ssel, float C1sel, float C0sel,
        float* __restrict__ outg, const TB& tb, int lane)
{
    bool flag = false;
    if (lane < NLEV) {
        const float mean = s * (1.0f / 1024.0f);
        const float var  = sq * (1.0f / 1024.0f) - mean * mean;
        const float rstd = 1.0f / sqrtf(var + 1e-5f);
        const float z = rstd * (Ssel - mean * C1sel) + C0sel;
        int cnt = 0;
        float mind = 1e30f;
        #pragma unroll
        for (int k = 0; k < 8; ++k) {
            cnt += (z > tb.t[k]) ? 1 : 0;
            mind = fminf(mind, fabsf(z - tb.t[k]));
        }
        outg[(size_t)row * NLEV + lane] = (float)(cnt - 4);
        flag = (mind < 1.0e-3f);   // fp32 z error ~1e-4 worst case
    }
    return flag;
}

// ---------------- fused: staggered waves + rolled prefetch + deferred repair ----
// R16 model (synthesis of R2/R5/R6/R7): clean configs all land ~75-78 us while
// per-SIMD issue time is only ~8 us -> SIMD idles >75% DESPITE 4-5 resident
// waves with latency/issue ~2.4 < wave count. Cause: PHASE-LOCKED waves. The
// prologue barrier aligns all 16 waves/CU; identical code keeps them locked
// (all stall on HBM together = VALUBusy 25% duty cycle); simultaneous load
// completion re-locks every iteration. R5's pairing null confirms (rescales
// the stall, doesn't break the lock). Fixes:
//  * one-time per-wave phase stagger after the prologue (s_sleep loop,
//    phase = wv + 8*(blockIdx&1) -> 0..960 cyc): stalls overlap other waves'
//    compute from the first row on.
//  * ROLLED one-row-ahead prefetch (R7's idea minus the full-unroll register
//    explosion): only one n*-copy exists, +16 VGPR.
//  * deferred fp64 repair via wave-uniform bitmask (R7, proven absmax=0).
//  * plain __launch_bounds__(512): R2's no-spill allocator config.
__global__ __launch_bounds__(512) void fsq_fused(
        const float* __restrict__ xg,
        const float* __restrict__ gg,
        const float* __restrict__ bg,
        const float* __restrict__ Wg,
        float* __restrict__ outg,
        int nrows, TB tb, TBD tbd)
{
    __shared__ float Vs[NLEV][D_DIM];     // 32 KB: V = g*W
    __shared__ float redc1[8][NLEV];
    __shared__ float redc0[8][NLEV];

    const int tid  = (int)threadIdx.x;
    const int lane = tid & 63;
    const int wv   = tid >> 6;            // 0..7

    // ---- stage V into LDS; block-reduce C1=sum(g*W), C0=sum(b*W) ----
    {
        const int col = tid * 2;          // 512 threads x 2 cols = 1024
        const float2 g2 = *(const float2*)(gg + col);
        const float2 b2 = *(const float2*)(bg + col);
        float pc1[NLEV], pc0[NLEV];
        #pragma unroll
        for (int n = 0; n < NLEV; ++n) {
            const float2 w2 = *(const float2*)(Wg + n * D_DIM + col);
            float2 v2;
            v2.x = g2.x * w2.x; v2.y = g2.y * w2.y;
            *(float2*)&Vs[n][col] = v2;
            pc1[n] = v2.x + v2.y;
            pc0[n] = b2.x * w2.x + b2.y * w2.y;
        }
        #pragma unroll
        for (int n = 0; n < NLEV; ++n) {
            pc1[n] = wave_allreduce(pc1[n]);
            pc0[n] = wave_allreduce(pc0[n]);
        }
        if (lane == 0) {
            #pragma unroll
            for (int n = 0; n < NLEV; ++n) { redc1[wv][n] = pc1[n]; redc0[wv][n] = pc0[n]; }
        }
    }
    __syncthreads();
    const int nsel = lane & 7;
    float C1sel = 0.f, C0sel = 0.f;
    #pragma unroll
    for (int w = 0; w < 8; ++w) { C1sel += redc1[w][nsel]; C0sel += redc0[w][nsel]; }

    // ---- desynchronize waves: one-time phase stagger (~64 cyc per step) ----
    {
        const int phase = wv + ((int)(blockIdx.x & 1) << 3);   // 0..15
        for (int i = 0; i < phase; ++i) __builtin_amdgcn_s_sleep(1);
    }

    // ---- hot loop: 8 rows/wave, rolled one-row-ahead prefetch ----
    const int wave_row0 = (int)blockIdx.x * 64 + wv * 8;
    const float4* xb = (const float4*)xg;
    const int lastr = nrows - 1;

    float4 c0, c1, c2, c3;
    {
        const int r = (wave_row0 <= lastr) ? wave_row0 : lastr;
        const float4* pr = xb + (size_t)r * (D_DIM / 4);
        c0 = pr[lane]; c1 = pr[64 + lane]; c2 = pr[128 + lane]; c3 = pr[192 + lane];
    }

    unsigned rmask = 0u;

    for (int p = 0; p < 8; ++p) {
        const int row = wave_row0 + p;

        // prefetch next row FIRST (in flight through this row's compute)
        float4 n0, n1, n2, n3;
        if (p < 7) {
            const int rn = (row + 1 <= lastr) ? row + 1 : lastr;
            const float4* pr = xb + (size_t)rn * (D_DIM / 4);
            n0 = pr[lane]; n1 = pr[64 + lane]; n2 = pr[128 + lane]; n3 = pr[192 + lane];
        }

        // compute current row
        float s = 0.f, sq = 0.f;
        float acc[NLEV];
        #pragma unroll
        for (int n = 0; n < NLEV; ++n) acc[n] = 0.f;

        #pragma unroll
        for (int j = 0; j < 4; ++j) {
            const float4 a = (j == 0) ? c0 : (j == 1) ? c1 : (j == 2) ? c2 : c3;
            const int vcol = j * 256 + lane * 4;
            s += (a.x + a.y) + (a.z + a.w);
            sq = fmaf(a.x, a.x, sq); sq = fmaf(a.y, a.y, sq);
            sq = fmaf(a.z, a.z, sq); sq = fmaf(a.w, a.w, sq);
            #pragma unroll
            for (int n = 0; n < NLEV; ++n) {
                const float4 v4 = *(const float4*)&Vs[n][vcol];  // ds_read_b128
                acc[n] = fmaf(a.x, v4.x, acc[n]);
                acc[n] = fmaf(a.y, v4.y, acc[n]);
                acc[n] = fmaf(a.z, v4.z, acc[n]);
                acc[n] = fmaf(a.w, v4.w, acc[n]);
            }
        }

        // within-16 DPP reduce, select n=(lane&7), finish with 2 shuffles
        s = red16(s); sq = red16(sq);
        #pragma unroll
        for (int n = 0; n < NLEV; ++n) acc[n] = red16(acc[n]);

        float u0 = (lane & 4) ? acc[4] : acc[0];
        float u1 = (lane & 4) ? acc[5] : acc[1];
        float u2 = (lane & 4) ? acc[6] : acc[2];
        float u3 = (lane & 4) ? acc[7] : acc[3];
        float w0 = (lane & 2) ? u2 : u0;
        float w1 = (lane & 2) ? u3 : u1;
        float Ssel = (lane & 1) ? w1 : w0;

        Ssel += __shfl_xor(Ssel, 16, 64); Ssel += __shfl_xor(Ssel, 32, 64);
        s    += __shfl_xor(s, 16, 64);    s    += __shfl_xor(s, 32, 64);
        sq   += __shfl_xor(sq, 16, 64);   sq   += __shfl_xor(sq, 32, 64);

        const bool flag = (row < nrows)
                        ? fast_epilogue(row, s, sq, Ssel, C1sel, C0sel, outg, tb, lane)
                        : false;
        if (__ballot(flag) != 0ULL) rmask |= (1u << p);   // wave-uniform

        if (p < 7) { c0 = n0; c1 = n1; c2 = n2; c3 = n3; }
    }

    // ---- deferred fp64 repairs (~4% of rows; wave-uniform mask loop) ----
    while (rmask) {
        const int p = __builtin_ctz(rmask);
        rmask &= rmask - 1u;
        repair_row_reload(wave_row0 + p, xg, gg, bg, Wg, outg, tbd, lane);
    }
}

extern "C" void kernel_launch(void* const* d_in, const int* in_sizes, int n_in,
                              void* d_out, int out_size, void* d_ws, size_t ws_size,
                              hipStream_t stream) {
    (void)n_in; (void)out_size; (void)d_ws; (void)ws_size;  // workspace UNUSED
    const float* regrs = (const float*)d_in[0];
    const float* ln_w  = (const float*)d_in[1];
    const float* ln_b  = (const float*)d_in[2];
    const float* W     = (const float*)d_in[3];
    float* out = (float*)d_out;

    const int nrows = in_sizes[0] / D_DIM;  // 32768
    const int nblocks = (nrows + 63) / 64;  // 64 rows/block -> 512 blocks (2/CU, all resident)

    TB tb; TBD tbd;
    for (int k = 0; k < 8; ++k) {
        const double y = ((double)k - 3.5) / 3.996;
        tbd.t[k] = atanh(y);           // fp64 z-space rounding boundaries
        tb.t[k]  = (float)tbd.t[k];
    }

    fsq_fused<<<nblocks, 512, 0, stream>>>(regrs, ln_w, ln_b, W, out, nrows, tb, tbd);
}

// Round 9
// 268.912 us; speedup vs baseline: 1.0117x; 1.0117x over previous
//
#include <hip/hip_runtime.h>
#include <math.h>

#define NLEV 8
#define D_DIM 1024

struct TB  { float  t[8]; };   // fp32 z-space thresholds (fast path)
struct TBD { double t[8]; };   // fp64 z-space thresholds (repair path)

// ---- DPP rotate-reduce within 16-lane rows (VALU pipe) ----
template<int CTRL>
__device__ __forceinline__ float ror_add(float v) {
    int r = __builtin_amdgcn_update_dpp(0, __float_as_int(v), CTRL, 0xF, 0xF, true);
    return v + __int_as_float(r);
}
__device__ __forceinline__ float red16(float v) {
    v = ror_add<0x121>(v);   // row_ror:1
    v = ror_add<0x122>(v);   // row_ror:2
    v = ror_add<0x124>(v);   // row_ror:4
    v = ror_add<0x128>(v);   // row_ror:8
    return v;                // all 16 lanes of each row hold the row sum
}
__device__ __forceinline__ float wave_allreduce(float v) {
    v = red16(v);
    v += __shfl_xor(v, 16, 64);
    v += __shfl_xor(v, 32, 64);
    return v;
}

// ---- fp64 repair, deferred: x RELOADED from global (L2/L3-hot here) ----
// Appears exactly once, AFTER the hot loop (outside it in program order),
// so the hot loop body stays small and nothing is live across it.
__device__ __forceinline__ void repair_row_reload(
        int row, const float* __restrict__ xg,
        const float* __restrict__ gg, const float* __restrict__ bg,
        const float* __restrict__ Wg, float* __restrict__ outg,
        const TBD& tbd, int lane)
{
    const float4* xb4 = (const float4*)(xg + (size_t)row * D_DIM);
    const float4 x0 = xb4[lane];
    const float4 x1 = xb4[64 + lane];
    const float4 x2 = xb4[128 + lane];
    const float4 x3 = xb4[192 + lane];

    double ds = 0.0, dsq = 0.0;
    #pragma unroll
    for (int j = 0; j < 4; ++j) {
        const float4 a = (j == 0) ? x0 : (j == 1) ? x1 : (j == 2) ? x2 : x3;
        const double v0 = (double)a.x, v1 = (double)a.y;
        const double v2 = (double)a.z, v3 = (double)a.w;
        ds += ((v0 + v1) + (v2 + v3));
        dsq = fma(v0, v0, dsq); dsq = fma(v1, v1, dsq);
        dsq = fma(v2, v2, dsq); dsq = fma(v3, v3, dsq);
    }
    #pragma unroll
    for (int off = 32; off >= 1; off >>= 1) {
        ds  += __shfl_xor(ds, off, 64);
        dsq += __shfl_xor(dsq, off, 64);
    }
    const double mean = ds * (1.0 / 1024.0);
    const double var  = dsq * (1.0 / 1024.0) - mean * mean;
    const double rstd = 1.0 / sqrt(var + 1e-5);

    double dacc[NLEV];
    #pragma unroll
    for (int n = 0; n < NLEV; ++n) dacc[n] = 0.0;
    #pragma unroll
    for (int j = 0; j < 4; ++j) {
        const int col = j * 256 + lane * 4;
        const float4 a = (j == 0) ? x0 : (j == 1) ? x1 : (j == 2) ? x2 : x3;
        const float4 g4 = *(const float4*)(gg + col);
        const float4 b4 = *(const float4*)(bg + col);
        const double y0 = fma(((double)a.x - mean) * rstd, (double)g4.x, (double)b4.x);
        const double y1 = fma(((double)a.y - mean) * rstd, (double)g4.y, (double)b4.y);
        const double y2 = fma(((double)a.z - mean) * rstd, (double)g4.z, (double)b4.z);
        const double y3 = fma(((double)a.w - mean) * rstd, (double)g4.w, (double)b4.w);
        #pragma unroll
        for (int n = 0; n < NLEV; ++n) {
            const float4 w4 = *(const float4*)(Wg + n * D_DIM + col);
            dacc[n] = fma(y0, (double)w4.x, dacc[n]);
            dacc[n] = fma(y1, (double)w4.y, dacc[n]);
            dacc[n] = fma(y2, (double)w4.z, dacc[n]);
            dacc[n] = fma(y3, (double)w4.w, dacc[n]);
        }
    }
    #pragma unroll
    for (int off = 32; off >= 1; off >>= 1) {
        #pragma unroll
        for (int n = 0; n < NLEV; ++n) dacc[n] += __shfl_xor(dacc[n], off, 64);
    }
    if (lane < NLEV) {
        double a0d = (lane & 4) ? dacc[4] : dacc[0];
        double a1d = (lane & 4) ? dacc[5] : dacc[1];
        double a2d = (lane & 4) ? dacc[6] : dacc[2];
        double a3d = (lane & 4) ? dacc[7] : dacc[3];
        double b0d = (lane & 2) ? a2d : a0d;
        double b1d = (lane & 2) ? a3d : a1d;
        const double z = (lane & 1) ? b1d : b0d;
        int c = 0;
        #pragma unroll
        for (int k = 0; k < 8; ++k) c += (z > tbd.t[k]) ? 1 : 0;
        outg[(size_t)row * NLEV + lane] = (float)(c - 4);
    }
}

// ---------------- fused: SMALL-CODE hot loop + deferred fp64 repair ----------
// R17 theory (re-synthesis of R1-R8): per-row cost is invariant to wave count
// (R1) AND to halved-LDS/doubled-ILP pairing (R5); every back-end pipe is idle
// (VALU 25%, LDS 26%, HBM 11%). The one thing all slow configs share: a fully
// unrolled hot body with inlined fp64 repair ≈ 54 KB of code — past the 32 KB
// I-cache. Front-end streams code from L2 every row; invariant to wave count
// (shared fetch) and pairing (same total bytes). Fixes:
//  * #pragma unroll 1 on the row loop -> one ~250-instr body (~2 KB), I$-hot.
//  * repair DEFERRED via wave-uniform rmask; fp64 body emitted ONCE, outside.
//  * NO prefetch (spilled in R6/R7/R8 — abandoned).
//  * one-time wave phase stagger (2 instrs) to break post-barrier phase-lock.
// Spill-gating prediction: VGPR ~72-88, WRITE_SIZE ~1.05 MB.
__global__ __launch_bounds__(512) void fsq_fused(
        const float* __restrict__ xg,
        const float* __restrict__ gg,
        const float* __restrict__ bg,
        const float* __restrict__ Wg,
        float* __restrict__ outg,
        int nrows, TB tb, TBD tbd)
{
    __shared__ float Vs[NLEV][D_DIM];     // 32 KB: V = g*W
    __shared__ float redc1[8][NLEV];
    __shared__ float redc0[8][NLEV];

    const int tid  = (int)threadIdx.x;
    const int lane = tid & 63;
    const int wv   = tid >> 6;            // 0..7

    // ---- stage V into LDS; block-reduce C1=sum(g*W), C0=sum(b*W) ----
    {
        const int col = tid * 2;          // 512 threads x 2 cols = 1024
        const float2 g2 = *(const float2*)(gg + col);
        const float2 b2 = *(const float2*)(bg + col);
        float pc1[NLEV], pc0[NLEV];
        #pragma unroll
        for (int n = 0; n < NLEV; ++n) {
            const float2 w2 = *(const float2*)(Wg + n * D_DIM + col);
            float2 v2;
            v2.x = g2.x * w2.x; v2.y = g2.y * w2.y;
            *(float2*)&Vs[n][col] = v2;
            pc1[n] = v2.x + v2.y;
            pc0[n] = b2.x * w2.x + b2.y * w2.y;
        }
        #pragma unroll
        for (int n = 0; n < NLEV; ++n) {
            pc1[n] = wave_allreduce(pc1[n]);
            pc0[n] = wave_allreduce(pc0[n]);
        }
        if (lane == 0) {
            #pragma unroll
            for (int n = 0; n < NLEV; ++n) { redc1[wv][n] = pc1[n]; redc0[wv][n] = pc0[n]; }
        }
    }
    __syncthreads();
    const int nsel = lane & 7;
    float C1sel = 0.f, C0sel = 0.f;
    #pragma unroll
    for (int w = 0; w < 8; ++w) { C1sel += redc1[w][nsel]; C0sel += redc0[w][nsel]; }

    // ---- desynchronize waves: one-time phase stagger (~64 cyc per step) ----
    {
        const int phase = wv + ((int)(blockIdx.x & 1) << 3);   // 0..15
        for (int i = 0; i < phase; ++i) __builtin_amdgcn_s_sleep(1);
    }

    // ---- hot loop: 8 rows/wave, ROLLED (small code), no prefetch ----
    const int wave_row0 = (int)blockIdx.x * 64 + wv * 8;
    const float4* xb = (const float4*)xg;
    unsigned rmask = 0u;

    #pragma unroll 1
    for (int p = 0; p < 8; ++p) {
        const int row = wave_row0 + p;
        const bool live = (row < nrows);
        const int r = live ? row : (nrows - 1);
        const float4* xr = xb + (size_t)r * (D_DIM / 4);
        const float4 c0 = xr[lane];
        const float4 c1 = xr[64 + lane];
        const float4 c2 = xr[128 + lane];
        const float4 c3 = xr[192 + lane];

        float s = 0.f, sq = 0.f;
        float acc[NLEV];
        #pragma unroll
        for (int n = 0; n < NLEV; ++n) acc[n] = 0.f;

        #pragma unroll
        for (int j = 0; j < 4; ++j) {
            const float4 a = (j == 0) ? c0 : (j == 1) ? c1 : (j == 2) ? c2 : c3;
            const int vcol = j * 256 + lane * 4;
            s += (a.x + a.y) + (a.z + a.w);
            sq = fmaf(a.x, a.x, sq); sq = fmaf(a.y, a.y, sq);
            sq = fmaf(a.z, a.z, sq); sq = fmaf(a.w, a.w, sq);
            #pragma unroll
            for (int n = 0; n < NLEV; ++n) {
                const float4 v4 = *(const float4*)&Vs[n][vcol];  // ds_read_b128
                acc[n] = fmaf(a.x, v4.x, acc[n]);
                acc[n] = fmaf(a.y, v4.y, acc[n]);
                acc[n] = fmaf(a.z, v4.z, acc[n]);
                acc[n] = fmaf(a.w, v4.w, acc[n]);
            }
        }

        // within-16 DPP reduce, select n=(lane&7), finish with 2 shuffles
        s = red16(s); sq = red16(sq);
        #pragma unroll
        for (int n = 0; n < NLEV; ++n) acc[n] = red16(acc[n]);

        float u0 = (lane & 4) ? acc[4] : acc[0];
        float u1 = (lane & 4) ? acc[5] : acc[1];
        float u2 = (lane & 4) ? acc[6] : acc[2];
        float u3 = (lane & 4) ? acc[7] : acc[3];
        float w0 = (lane & 2) ? u2 : u0;
        float w1 = (lane & 2) ? u3 : u1;
        float Ssel = (lane & 1) ? w1 : w0;

        Ssel += __shfl_xor(Ssel, 16, 64); Ssel += __shfl_xor(Ssel, 32, 64);
        s    += __shfl_xor(s, 16, 64);    s    += __shfl_xor(s, 32, 64);
        sq   += __shfl_xor(sq, 16, 64);   sq   += __shfl_xor(sq, 32, 64);

        bool flag = false;
        if (live && lane < NLEV) {
            const float mean = s * (1.0f / 1024.0f);
            const float var  = sq * (1.0f / 1024.0f) - mean * mean;
            const float rstd = 1.0f / sqrtf(var + 1e-5f);
            const float z = rstd * (Ssel - mean * C1sel) + C0sel;
            int cnt = 0;
            float mind = 1e30f;
            #pragma unroll
            for (int k = 0; k < 8; ++k) {
                cnt += (z > tb.t[k]) ? 1 : 0;
                mind = fminf(mind, fabsf(z - tb.t[k]));
            }
            outg[(size_t)row * NLEV + lane] = (float)(cnt - 4);
            flag = (mind < 1.0e-3f);   // fp32 z error ~1e-4 worst case
        }
        if (__ballot(flag) != 0ULL) rmask |= (1u << p);   // wave-uniform
    }

    // ---- deferred fp64 repairs (~4% of rows; wave-uniform mask loop) ----
    while (rmask) {
        const int p = __builtin_ctz(rmask);
        rmask &= rmask - 1u;
        repair_row_reload(wave_row0 + p, xg, gg, bg, Wg, outg, tbd, lane);
    }
}

extern "C" void kernel_launch(void* const* d_in, const int* in_sizes, int n_in,
                              void* d_out, int out_size, void* d_ws, size_t ws_size,
                              hipStream_t stream) {
    (void)n_in; (void)out_size; (void)d_ws; (void)ws_size;  // workspace UNUSED
    const float* regrs = (const float*)d_in[0];
    const float* ln_w  = (const float*)d_in[1];
    const float* ln_b  = (const float*)d_in[2];
    const float* W     = (const float*)d_in[3];
    float* out = (float*)d_out;

    const int nrows = in_sizes[0] / D_DIM;  // 32768
    const int nblocks = (nrows + 63) / 64;  // 64 rows/block -> 512 blocks (2/CU, all resident)

    TB tb; TBD tbd;
    for (int k = 0; k < 8; ++k) {
        const double y = ((double)k - 3.5) / 3.996;
        tbd.t[k] = atanh(y);           // fp64 z-space rounding boundaries
        tb.t[k]  = (float)tbd.t[k];
    }

    fsq_fused<<<nblocks, 512, 0, stream>>>(regrs, ln_w, ln_b, W, out, nrows, tb, tbd);
}

// Round 10
// 216.869 us; speedup vs baseline: 1.2545x; 1.2400x over previous
//
#include <hip/hip_runtime.h>
#include <math.h>

#define NLEV 8
#define D_DIM 1024

struct TB  { float  t[8]; };   // fp32 z-space thresholds (fast path)
struct TBD { double t[8]; };   // fp64 z-space thresholds (repair path)

// ---- DPP rotate-reduce within 16-lane rows (VALU pipe) ----
template<int CTRL>
__device__ __forceinline__ float ror_add(float v) {
    int r = __builtin_amdgcn_update_dpp(0, __float_as_int(v), CTRL, 0xF, 0xF, true);
    return v + __int_as_float(r);
}
__device__ __forceinline__ float red16(float v) {
    v = ror_add<0x121>(v);   // row_ror:1
    v = ror_add<0x122>(v);   // row_ror:2
    v = ror_add<0x124>(v);   // row_ror:4
    v = ror_add<0x128>(v);   // row_ror:8
    return v;                // all 16 lanes of each row hold the row sum
}
__device__ __forceinline__ float wave_allreduce(float v) {
    v = red16(v);
    v += __shfl_xor(v, 16, 64);
    v += __shfl_xor(v, 32, 64);
    return v;
}

// ---------------- fused: R2 (verified clean: VGPR 92, WRITE 1.04 MB) + stagger ----
// R18: R7/R8/R9 all failed their spill gates (VGPR 128, WRITE 36+ MB) -> every
// stagger/I$/prefetch test was confounded by scratch traffic. The ONLY clean
// 512-thread config is R2 (inline per-row repair, plain bounds, 4 rows/wave).
// This round = R2 byte-identical + ONE variable: a 2-instruction one-time wave
// phase stagger after the prologue barrier.
// Phase-lock theory (last structural theory standing): per wave ~600 issue cyc
// per ~1400-cyc row period = 43% duty; 4 waves/SIMD should saturate the SIMD
// UNLESS they stall in unison (post-barrier lockstep, re-locked each row by
// simultaneous load completion). VALUBusy 25% + all-pipes-idle matches.
// Gate: VGPR=92, WRITE~1.04 MB. Success: fused 78 -> 45-60 us. Null+clean:
// phase-lock dead, source-level levers exhausted.
__global__ __launch_bounds__(512) void fsq_fused(
        const float* __restrict__ xg,
        const float* __restrict__ gg,
        const float* __restrict__ bg,
        const float* __restrict__ Wg,
        float* __restrict__ outg,
        int nrows, TB tb, TBD tbd)
{
    __shared__ float Vs[NLEV][D_DIM];     // 32 KB: V = g*W
    __shared__ float redc1[8][NLEV];
    __shared__ float redc0[8][NLEV];

    const int tid  = (int)threadIdx.x;
    const int lane = tid & 63;
    const int wv   = tid >> 6;            // 0..7

    // ---- stage V into LDS; block-reduce C1=sum(g*W), C0=sum(b*W) ----
    {
        const int col = tid * 2;          // 512 threads x 2 cols = 1024
        const float2 g2 = *(const float2*)(gg + col);
        const float2 b2 = *(const float2*)(bg + col);
        float pc1[NLEV], pc0[NLEV];
        #pragma unroll
        for (int n = 0; n < NLEV; ++n) {
            const float2 w2 = *(const float2*)(Wg + n * D_DIM + col);
            float2 v2;
            v2.x = g2.x * w2.x; v2.y = g2.y * w2.y;
            *(float2*)&Vs[n][col] = v2;
            pc1[n] = v2.x + v2.y;
            pc0[n] = b2.x * w2.x + b2.y * w2.y;
        }
        #pragma unroll
        for (int n = 0; n < NLEV; ++n) {
            pc1[n] = wave_allreduce(pc1[n]);
            pc0[n] = wave_allreduce(pc0[n]);
        }
        if (lane == 0) {
            #pragma unroll
            for (int n = 0; n < NLEV; ++n) { redc1[wv][n] = pc1[n]; redc0[wv][n] = pc0[n]; }
        }
    }
    __syncthreads();
    const int nsel = lane & 7;
    float C1sel = 0.f, C0sel = 0.f;
    #pragma unroll
    for (int w = 0; w < 8; ++w) { C1sel += redc1[w][nsel]; C0sel += redc0[w][nsel]; }

    // ---- ONE-VARIABLE CHANGE vs R2: one-time wave phase stagger ----
    {
        const int phase = wv + ((int)(blockIdx.x & 1) << 3);   // 0..15 (~64 cyc/step)
        for (int i = 0; i < phase; ++i) __builtin_amdgcn_s_sleep(1);
    }

    // ---- row loop: 4 rows per wave, one at a time (exact R2 structure) ----
    const long wave_row0 = (long)blockIdx.x * 32 + (long)wv * 4;
    const float4* xb = (const float4*)xg;

    for (int p = 0; p < 4; ++p) {
        const long row = wave_row0 + p;
        if (row >= nrows) break;

        const float4* xr = xb + row * (D_DIM / 4);
        float4 xv0 = xr[lane];
        float4 xv1 = xr[64 + lane];
        float4 xv2 = xr[128 + lane];
        float4 xv3 = xr[192 + lane];

        float s = 0.f, sq = 0.f;
        float acc[NLEV];
        #pragma unroll
        for (int n = 0; n < NLEV; ++n) acc[n] = 0.f;

        #pragma unroll
        for (int j = 0; j < 4; ++j) {
            const float4 a = (j == 0) ? xv0 : (j == 1) ? xv1 : (j == 2) ? xv2 : xv3;
            const int vcol = j * 256 + lane * 4;
            s += (a.x + a.y) + (a.z + a.w);
            sq = fmaf(a.x, a.x, sq); sq = fmaf(a.y, a.y, sq);
            sq = fmaf(a.z, a.z, sq); sq = fmaf(a.w, a.w, sq);
            #pragma unroll
            for (int n = 0; n < NLEV; ++n) {
                const float4 v4 = *(const float4*)&Vs[n][vcol];  // ds_read_b128
                acc[n] = fmaf(a.x, v4.x, acc[n]);
                acc[n] = fmaf(a.y, v4.y, acc[n]);
                acc[n] = fmaf(a.z, v4.z, acc[n]);
                acc[n] = fmaf(a.w, v4.w, acc[n]);
            }
        }

        // within-16 DPP reduce, select n=(lane&7), finish with 2 shuffles
        s = red16(s); sq = red16(sq);
        #pragma unroll
        for (int n = 0; n < NLEV; ++n) acc[n] = red16(acc[n]);

        float u0 = (lane & 4) ? acc[4] : acc[0];
        float u1 = (lane & 4) ? acc[5] : acc[1];
        float u2 = (lane & 4) ? acc[6] : acc[2];
        float u3 = (lane & 4) ? acc[7] : acc[3];
        float w0 = (lane & 2) ? u2 : u0;
        float w1 = (lane & 2) ? u3 : u1;
        float Ssel = (lane & 1) ? w1 : w0;

        Ssel += __shfl_xor(Ssel, 16, 64); Ssel += __shfl_xor(Ssel, 32, 64);
        s    += __shfl_xor(s, 16, 64);    s    += __shfl_xor(s, 32, 64);
        sq   += __shfl_xor(sq, 16, 64);   sq   += __shfl_xor(sq, 32, 64);

        bool flag = false;
        int  cnt_fast = 0;
        if (lane < NLEV) {
            const float mean = s * (1.0f / 1024.0f);
            const float var  = sq * (1.0f / 1024.0f) - mean * mean;
            const float rstd = 1.0f / sqrtf(var + 1e-5f);
            const float z = rstd * (Ssel - mean * C1sel) + C0sel;
            float mind = 1e30f;
            #pragma unroll
            for (int k = 0; k < 8; ++k) {
                cnt_fast += (z > tb.t[k]) ? 1 : 0;
                mind = fminf(mind, fabsf(z - tb.t[k]));
            }
            flag = (mind < 1.0e-3f);   // fp32 z error ~1e-4 worst case
        }
        const unsigned long long bal = __ballot(flag);

        if (bal == 0ULL) {
            // fast path: fp32 result is unambiguous
            if (lane < NLEV) outg[row * NLEV + lane] = (float)(cnt_fast - 4);
        } else {
            // ---- inline fp64 repair (wave-uniform branch, x already in regs) ----
            double ds = 0.0, dsq = 0.0;
            #pragma unroll
            for (int j = 0; j < 4; ++j) {
                const float4 a = (j == 0) ? xv0 : (j == 1) ? xv1 : (j == 2) ? xv2 : xv3;
                const double x0 = (double)a.x, x1 = (double)a.y;
                const double x2 = (double)a.z, x3 = (double)a.w;
                ds += ((x0 + x1) + (x2 + x3));
                dsq = fma(x0, x0, dsq); dsq = fma(x1, x1, dsq);
                dsq = fma(x2, x2, dsq); dsq = fma(x3, x3, dsq);
            }
            #pragma unroll
            for (int off = 32; off >= 1; off >>= 1) {
                ds  += __shfl_xor(ds, off, 64);
                dsq += __shfl_xor(dsq, off, 64);
            }
            const double mean = ds * (1.0 / 1024.0);
            const double var  = dsq * (1.0 / 1024.0) - mean * mean;
            const double rstd = 1.0 / sqrt(var + 1e-5);

            double dacc[NLEV];
            #pragma unroll
            for (int n = 0; n < NLEV; ++n) dacc[n] = 0.0;
            #pragma unroll
            for (int j = 0; j < 4; ++j) {
                const int col = j * 256 + lane * 4;
                const float4 a = (j == 0) ? xv0 : (j == 1) ? xv1 : (j == 2) ? xv2 : xv3;
                const float4 g4 = *(const float4*)(gg + col);
                const float4 b4 = *(const float4*)(bg + col);
                const double y0 = fma(((double)a.x - mean) * rstd, (double)g4.x, (double)b4.x);
                const double y1 = fma(((double)a.y - mean) * rstd, (double)g4.y, (double)b4.y);
                const double y2 = fma(((double)a.z - mean) * rstd, (double)g4.z, (double)b4.z);
                const double y3 = fma(((double)a.w - mean) * rstd, (double)g4.w, (double)b4.w);
                #pragma unroll
                for (int n = 0; n < NLEV; ++n) {
                    const float4 w4 = *(const float4*)(Wg + n * D_DIM + col);
                    dacc[n] = fma(y0, (double)w4.x, dacc[n]);
                    dacc[n] = fma(y1, (double)w4.y, dacc[n]);
                    dacc[n] = fma(y2, (double)w4.z, dacc[n]);
                    dacc[n] = fma(y3, (double)w4.w, dacc[n]);
                }
            }
            #pragma unroll
            for (int off = 32; off >= 1; off >>= 1) {
                #pragma unroll
                for (int n = 0; n < NLEV; ++n) dacc[n] += __shfl_xor(dacc[n], off, 64);
            }
            if (lane < NLEV) {
                double a0 = (lane & 4) ? dacc[4] : dacc[0];
                double a1 = (lane & 4) ? dacc[5] : dacc[1];
                double a2 = (lane & 4) ? dacc[6] : dacc[2];
                double a3 = (lane & 4) ? dacc[7] : dacc[3];
                double b0 = (lane & 2) ? a2 : a0;
                double b1 = (lane & 2) ? a3 : a1;
                const double z = (lane & 1) ? b1 : b0;
                int c = 0;
                #pragma unroll
                for (int k = 0; k < 8; ++k) c += (z > tbd.t[k]) ? 1 : 0;
                outg[row * NLEV + lane] = (float)(c - 4);
            }
        }
    }
}

extern "C" void kernel_launch(void* const* d_in, const int* in_sizes, int n_in,
                              void* d_out, int out_size, void* d_ws, size_t ws_size,
                              hipStream_t stream) {
    (void)n_in; (void)out_size; (void)d_ws; (void)ws_size;  // workspace UNUSED
    const float* regrs = (const float*)d_in[0];
    const float* ln_w  = (const float*)d_in[1];
    const float* ln_b  = (const float*)d_in[2];
    const float* W     = (const float*)d_in[3];
    float* out = (float*)d_out;

    const int nrows = in_sizes[0] / D_DIM;  // 32768
    const int nblocks = (nrows + 31) / 32;  // 32 rows/block -> 1024 blocks

    TB tb; TBD tbd;
    for (int k = 0; k < 8; ++k) {
        const double y = ((double)k - 3.5) / 3.996;
        tbd.t[k] = atanh(y);           // fp64 z-space rounding boundaries
        tb.t[k]  = (float)tbd.t[k];
    }

    fsq_fused<<<nblocks, 512, 0, stream>>>(regrs, ln_w, ln_b, W, out, nrows, tb, tbd);
}